// Round 7
// baseline (356.984 us; speedup 1.0000x reference)
//
#include <hip/hip_runtime.h>
#include <hip/hip_bf16.h>
#include <stdint.h>

// Problem constants
constexpr int IN_DIM   = 2048;
constexpr int OUT_DIM  = 2048;
constexpr int BATCH    = 4096;
constexpr int KDIM     = 2 * IN_DIM;   // concatenated K: [xn | S] vs [scale_base | Wd]
constexpr float LN_EPS = 1e-5f;

// GEMM tile: 256x128 block, 4 waves (2x2), 128x64 per wave, BK=32.
#define TM 256
#define TN 128
#define BK 32
constexpr int NK    = KDIM / BK;       // 128 k-steps
constexpr int ASLOT = TM * BK;         // 8192 shorts (16 KB)
constexpr int BSLOT = TN * BK;         // 4096 shorts (8 KB)

typedef __attribute__((ext_vector_type(8))) short  short8;  // 8 x bf16 (4 VGPRs)
typedef __attribute__((ext_vector_type(4))) float  f32x4;   // MFMA accumulator

__device__ __forceinline__ unsigned short f2bf(float f) {
  __hip_bfloat16 h = __float2bfloat16(f);
  return *reinterpret_cast<unsigned short*>(&h);
}
__device__ __forceinline__ unsigned pack2bf(float a, float b) {
  return (unsigned)f2bf(a) | ((unsigned)f2bf(b) << 16);
}

// ---------------------------------------------------------------------------
// Kernel 1 (FUSED prep): blocks [0, BATCH) do LayerNorm+RBF rows;
// blocks [BATCH, ...) pack B = [scale_base | Wd] (Wd = sum_g spline_weight).
// ---------------------------------------------------------------------------
constexpr int SW_F4   = OUT_DIM * IN_DIM * 2;   // float4 count of spline_weight
constexpr int SB_F4   = OUT_DIM * IN_DIM / 4;   // float4 count of scale_base
constexpr int PACK_BLOCKS = (SW_F4 + SB_F4) / 256;

__global__ __launch_bounds__(256) void prep_kernel(
    const float* __restrict__ x, const float* __restrict__ lnw,
    const float* __restrict__ lnb, const float* __restrict__ betap,
    const float* __restrict__ grid, unsigned short* __restrict__ A,
    const float* __restrict__ sw, const float* __restrict__ sb,
    unsigned* __restrict__ Bu)    // B as uint (2 bf16 per uint), OUT x KDIM/2
{
  const int tid = threadIdx.x;
  if (blockIdx.x < BATCH) {
    // ----------------------- LayerNorm + RBF path -----------------------
    const int row = blockIdx.x;
    const float4* xr = reinterpret_cast<const float4*>(x + (size_t)row * IN_DIM);
    float4 v0 = xr[tid];
    float4 v1 = xr[tid + 256];
    float s = (v0.x + v0.y) + (v0.z + v0.w) + (v1.x + v1.y) + (v1.z + v1.w);
    float q = v0.x * v0.x + v0.y * v0.y + v0.z * v0.z + v0.w * v0.w
            + v1.x * v1.x + v1.y * v1.y + v1.z * v1.z + v1.w * v1.w;
    #pragma unroll
    for (int off = 32; off > 0; off >>= 1) {
      s += __shfl_down(s, off, 64);
      q += __shfl_down(q, off, 64);
    }
    __shared__ float red[10];
    const int lane = tid & 63, wv = tid >> 6;
    if (lane == 0) { red[wv] = s; red[4 + wv] = q; }
    __syncthreads();
    if (tid == 0) {
      float ts = (red[0] + red[1]) + (red[2] + red[3]);
      float tq = (red[4] + red[5]) + (red[6] + red[7]);
      float mu  = ts * (1.0f / IN_DIM);
      float var = tq * (1.0f / IN_DIM) - mu * mu;
      red[8] = mu;
      red[9] = rsqrtf(var + LN_EPS);
    }
    __syncthreads();
    const float mu = red[8], rs = red[9];
    const float beta = fminf(fmaxf(betap[0], 0.5f), 6.0f);
    float g[8];
    #pragma unroll
    for (int i = 0; i < 8; i++) g[i] = grid[i];
    const float4* w4 = reinterpret_cast<const float4*>(lnw);
    const float4* b4 = reinterpret_cast<const float4*>(lnb);
    unsigned short* Ar = A + (size_t)row * KDIM;
    #pragma unroll
    for (int h = 0; h < 2; h++) {
      const int idx = tid + h * 256;        // float4 index within the row
      float4 xv  = (h == 0) ? v0 : v1;
      float4 wv4 = w4[idx];
      float4 bv4 = b4[idx];
      float xa[4] = {xv.x, xv.y, xv.z, xv.w};
      float wa[4] = {wv4.x, wv4.y, wv4.z, wv4.w};
      float ba[4] = {bv4.x, bv4.y, bv4.z, bv4.w};
      float xn[4], S[4];
      #pragma unroll
      for (int c = 0; c < 4; c++) {
        float xnv = (xa[c] - mu) * rs * wa[c] + ba[c];
        xn[c] = xnv;
        float acc = 0.f;
        #pragma unroll
        for (int gg = 0; gg < 8; gg++) {
          float d = xnv - g[gg];
          acc += __expf(-beta * d * d);
        }
        S[c] = acc;
      }
      uint2 px, ps;
      px.x = pack2bf(xn[0], xn[1]);
      px.y = pack2bf(xn[2], xn[3]);
      ps.x = pack2bf(S[0], S[1]);
      ps.y = pack2bf(S[2], S[3]);
      *reinterpret_cast<uint2*>(Ar + idx * 4) = px;
      *reinterpret_cast<uint2*>(Ar + IN_DIM + idx * 4) = ps;
    }
  } else {
    // --------------------------- B-pack path ---------------------------
    const int g = (blockIdx.x - BATCH) * 256 + tid;
    const int lane = tid & 63;
    if (g < SW_F4) {
      float4 v = reinterpret_cast<const float4*>(sw)[g];
      float s = (v.x + v.y) + (v.z + v.w);
      s += __shfl_xor(s, 1, 64);               // full Wd[i] in both lanes of pair
      float hi = __shfl_down(s, 2, 64);        // Wd of i+1 for even-pair lanes
      if ((lane & 3) == 0) {
        const int i_lin = g >> 1;              // linear (o,i)
        const int o = i_lin >> 11;             // / IN_DIM
        const int i = i_lin & (IN_DIM - 1);
        Bu[(size_t)o * (KDIM / 2) + (IN_DIM / 2) + (i >> 1)] = pack2bf(s, hi);
      }
    } else {
      const int t = g - SW_F4;                 // [0, SB_F4)
      float4 v = reinterpret_cast<const float4*>(sb)[t];
      const int o  = t >> 9;                   // 512 float4 per sb row
      const int i4 = t & 511;
      uint2 u;
      u.x = pack2bf(v.x, v.y);
      u.y = pack2bf(v.z, v.w);
      *reinterpret_cast<uint2*>(&Bu[(size_t)o * (KDIM / 2) + i4 * 2]) = u;
    }
  }
}

// ---------------------------------------------------------------------------
// Kernel 2: C = A @ B^T + bias. 256x128 block tile, 4 waves of 128x64
// (acc 8x4 of 16x16), BK=32, double-buffered (48 KB LDS), one barrier/stage.
// WHY: the 64x64/wave scheme is LDS-throughput-bound (~96 KB/block-stage at
// ~85 B/cyc ≈ 62 µs floor — matches R3/R4/R5 all plateauing at 70-92 µs).
// 128x64/wave cuts LDS bytes/FLOP 26% (reads/wave-stage (Mw+Nw)/(Mw*Nw)).
// LDS layout: R5's paired-row BK=32 XOR swizzle (measured 0 conflicts):
// rows 2r,2r+1 share a 128-B line; granule gi=(row&1)*4+kg stored at
// gi^(line&7). Swizzle folded into producer GLOBAL addresses (gld_lds dest
// is wave-uniform base + lane*16 [m104/m108]).
// Grid 256 blocks = 1/CU; XCD map: each XCD owns a 4(bm)x8(bn) rectangle.
// ---------------------------------------------------------------------------
__device__ __forceinline__ void gld_lds16(const unsigned short* g, unsigned short* l) {
  __builtin_amdgcn_global_load_lds(
      (const __attribute__((address_space(1))) void*)g,
      (__attribute__((address_space(3))) void*)l, 16, 0, 0);
}

__global__ __launch_bounds__(256) void gemm_kernel(
    const unsigned short* __restrict__ A, const unsigned short* __restrict__ Bm,
    const float* __restrict__ bias, float* __restrict__ out)
{
  __shared__ __align__(16) unsigned short As[2 * ASLOT];   // 32 KB
  __shared__ __align__(16) unsigned short Bs[2 * BSLOT];   // 16 KB
  const int tid  = threadIdx.x;
  const int lane = tid & 63;
  const int wv   = tid >> 6;
  const int wr   = wv >> 1;        // wave row: 0,1 -> 128 rows each
  const int wc   = wv & 1;         // wave col: 0,1 -> 64 cols each
  // XCD rectangle swizzle: d%8 = XCD [m09]; XCD x owns bm in [(x>>1)*4,+4),
  // bn in [(x&1)*8,+8). Bijective over the 16x16 block grid.
  const int d  = blockIdx.x;
  const int x  = d & 7, q = d >> 3;
  const int m0 = (((x >> 1) * 4) + (q & 3)) * TM;
  const int n0 = (((x & 1) * 8) + (q >> 2)) * TN;
  const int lrow = lane & 15;      // fragment m / n index
  const int lkq  = lane >> 4;      // 16-B k-granule index (0..3)

  f32x4 acc[8][4] = {};

  // Staging: A = 1024 16-B segs/stage (4/thread), B = 512 (2/thread).
  const unsigned short* Ap[4];
  const unsigned short* Bp[2];
  unsigned aB[4], bB[2];           // wave-uniform LDS short offsets (slot 0)
  #pragma unroll
  for (int j = 0; j < 4; j++) {
    const int seg  = j * 256 + wv * 64 + lane;
    const int line = seg >> 3;
    const int gi   = (seg & 7) ^ (line & 7);
    const int row  = line * 2 + (gi >> 2);
    const int kg   = gi & 3;
    Ap[j] = A + (size_t)(m0 + row) * KDIM + kg * 8;
    aB[j] = (unsigned)((j * 256 + wv * 64) * 8);
  }
  #pragma unroll
  for (int j = 0; j < 2; j++) {
    const int seg  = j * 256 + wv * 64 + lane;
    const int line = seg >> 3;
    const int gi   = (seg & 7) ^ (line & 7);
    const int row  = line * 2 + (gi >> 2);
    const int kg   = gi & 3;
    Bp[j] = Bm + (size_t)(n0 + row) * KDIM + kg * 8;
    bB[j] = (unsigned)((j * 256 + wv * 64) * 8);
  }

  // Consumer fragment offsets (slot-relative, swizzled).
  unsigned aOff[8], bOff[4];
  #pragma unroll
  for (int i = 0; i < 8; i++) {
    const int ra = wr * 128 + i * 16 + lrow;
    const int la = ra >> 1, ga = (ra & 1) * 4 + lkq;
    aOff[i] = (unsigned)(la * 64 + (ga ^ (la & 7)) * 8);
  }
  #pragma unroll
  for (int i = 0; i < 4; i++) {
    const int rb = wc * 64 + i * 16 + lrow;
    const int lb = rb >> 1, gb = (rb & 1) * 4 + lkq;
    bOff[i] = (unsigned)(lb * 64 + (gb ^ (lb & 7)) * 8);
  }

  // Prologue: stage 0 into buffer 0.
  #pragma unroll
  for (int j = 0; j < 4; j++) gld_lds16(Ap[j], &As[aB[j]]);
  #pragma unroll
  for (int j = 0; j < 2; j++) gld_lds16(Bp[j], &Bs[bB[j]]);

  #pragma unroll 1
  for (int kt = 0; kt < NK; kt++) {
    __syncthreads();               // drains stage-kt loads (issued a stage ago)
    const unsigned ca = (kt & 1) * ASLOT;
    const unsigned cb = (kt & 1) * BSLOT;
    if (kt + 1 < NK) {             // prefetch stage kt+1 into other buffer
      const unsigned na = ((kt + 1) & 1) * ASLOT;
      const unsigned nb = ((kt + 1) & 1) * BSLOT;
      const int koff = (kt + 1) * BK;
      #pragma unroll
      for (int j = 0; j < 4; j++) gld_lds16(Ap[j] + koff, &As[na + aB[j]]);
      #pragma unroll
      for (int j = 0; j < 2; j++) gld_lds16(Bp[j] + koff, &Bs[nb + bB[j]]);
    }

    short8 af[8], bf[4];
    #pragma unroll
    for (int mi = 0; mi < 8; mi++)
      af[mi] = *reinterpret_cast<const short8*>(&As[ca + aOff[mi]]);
    #pragma unroll
    for (int ni = 0; ni < 4; ni++)
      bf[ni] = *reinterpret_cast<const short8*>(&Bs[cb + bOff[ni]]);

    #pragma unroll
    for (int mi = 0; mi < 8; mi++)
      #pragma unroll
      for (int ni = 0; ni < 4; ni++)
        acc[mi][ni] = __builtin_amdgcn_mfma_f32_16x16x32_bf16(
            af[mi], bf[ni], acc[mi][ni], 0, 0, 0);
  }

  // Epilogue: C/D layout col=lane&15, row=(lane>>4)*4+reg  [measured m89/m91]
  const int rbse = (lane >> 4) * 4;
  #pragma unroll
  for (int ni = 0; ni < 4; ni++) {
    const int col = n0 + wc * 64 + ni * 16 + lrow;
    const float bv = bias[col];
    #pragma unroll
    for (int mi = 0; mi < 8; mi++) {
      const int rowm = m0 + wr * 128 + mi * 16 + rbse;
      #pragma unroll
      for (int r = 0; r < 4; r++)
        out[(size_t)(rowm + r) * OUT_DIM + col] = acc[mi][ni][r] + bv;
    }
  }
}

// ---------------------------------------------------------------------------
extern "C" void kernel_launch(void* const* d_in, const int* in_sizes, int n_in,
                              void* d_out, int out_size, void* d_ws, size_t ws_size,
                              hipStream_t stream) {
  const float* x    = (const float*)d_in[0];
  const float* lnw  = (const float*)d_in[1];
  const float* lnb  = (const float*)d_in[2];
  const float* sw   = (const float*)d_in[3];   // (OUT, IN, 8)
  const float* sb   = (const float*)d_in[4];   // (OUT, IN)
  const float* bias = (const float*)d_in[5];   // (OUT,)
  const float* beta = (const float*)d_in[6];   // (1,)
  const float* grid = (const float*)d_in[7];   // (8,)
  float* out = (float*)d_out;

  unsigned short* A = (unsigned short*)d_ws;               // BATCH x KDIM bf16 (33.5 MB)
  unsigned short* B = A + (size_t)BATCH * KDIM;            // OUT   x KDIM bf16 (16.8 MB)

  hipLaunchKernelGGL(prep_kernel, dim3(BATCH + PACK_BLOCKS), dim3(256), 0, stream,
                     x, lnw, lnb, beta, grid, A, sw, sb, (unsigned*)B);
  hipLaunchKernelGGL(gemm_kernel, dim3((BATCH / TM) * (OUT_DIM / TN)), dim3(256), 0, stream,
                     A, B, bias, out);
}